// Round 1
// baseline (82772.052 us; speedup 1.0000x reference)
//
#include <hip/hip_runtime.h>
#include <hip/hip_cooperative_groups.h>
#include <cmath>

namespace cg = cooperative_groups;

#define BATCH 256
#define SEQT  512
#define HID   512
#define NTHR  512
#define GB    16     // batches per batch-group
#define QW    32     // h-indices per WG slice
#define HPAD  516    // LDS row stride (bank-conflict-free, 16B aligned)

// Stage h[GB][HID] from global into LDS (coalesced float4).
__device__ __forceinline__ void stage_h(float (*hs)[HPAD], const float* __restrict__ src)
{
    #pragma unroll
    for (int r = 0; r < 4; ++r) {
        int idx = r * NTHR + threadIdx.x;     // 0..2047 float4s
        int b   = idx >> 7;                   // /128 float4 per row
        int kq  = idx & 127;
        *(float4*)&hs[b][kq * 4] = *(const float4*)&src[b * HID + kq * 4];
    }
}

__device__ __forceinline__ float sigm(float v) { return 1.0f / (1.0f + expf(-v)); }

__global__ void __launch_bounds__(NTHR, 1)
lstm2_kernel(const float* __restrict__ x,
             const float* __restrict__ Wih0, const float* __restrict__ Whh0,
             const float* __restrict__ bih0, const float* __restrict__ bhh0,
             const float* __restrict__ Wih1, const float* __restrict__ Whh1,
             const float* __restrict__ bih1, const float* __restrict__ bhh1,
             const float* __restrict__ Wfc,  const float* __restrict__ bfc,
             float* __restrict__ out, float* __restrict__ ws)
{
    cg::grid_group grid = cg::this_grid();

    __shared__ float hs[GB][HPAD];     // 33.0 KB
    __shared__ float gbuf[GB][132];    //  8.4 KB

    const int tid = threadIdx.x;
    const int wg  = blockIdx.x;
    const int ig  = wg >> 4;           // batch group 0..15
    const int j   = wg & 15;           // h-slice 0..15
    const int b0  = ig * GB;

    // K-loop mapping: 32 row-slots x 16 batches
    const int slot = tid >> 4;         // 0..31 -> 4 rows each
    const int bb   = tid & 15;         // batch within group

    // update mapping: 16 batches x 32 q
    const int ub   = tid >> 5;         // 0..15
    const int uq   = tid & 31;         // 0..31
    const int qabs = j * QW + uq;

    float* h1ws = ws;                          // [2][BATCH][HID]
    float* h2ws = ws + 2 * BATCH * HID;        // [2][BATCH][HID]

    float c1 = 0.f, c2 = 0.f;                  // cell state lives in registers

    int grows[4];
    #pragma unroll
    for (int u = 0; u < 4; ++u) {
        int rr128 = slot * 4 + u;              // 0..127 within WG row-set
        int m  = rr128 >> 5;                   // gate block 0..3 (i,f,g,o)
        int rr = rr128 & 31;
        grows[u] = m * 512 + j * QW + rr;      // absolute gate row 0..2047
    }

    // Hoisted small constants (L2-hot anyway, but keep them in regs)
    float bias1[4], bias2[4], wx[4][3];
    #pragma unroll
    for (int u = 0; u < 4; ++u) {
        bias1[u] = bih0[grows[u]] + bhh0[grows[u]];
        bias2[u] = bih1[grows[u]] + bhh1[grows[u]];
        wx[u][0] = Wih0[grows[u] * 3 + 0];
        wx[u][1] = Wih0[grows[u] * 3 + 1];
        wx[u][2] = Wih0[grows[u] * 3 + 2];
    }
    const float wfc0 = Wfc[0 * HID + qabs];
    const float wfc1 = Wfc[1 * HID + qabs];
    const float wfc2 = Wfc[2 * HID + qabs];

    for (int t = 0; t < SEQT; ++t) {
        const int rs  = t & 1;
        const int wsl = 1 - rs;

        // ====================== Layer 1 ======================
        stage_h(hs, h1ws + rs * BATCH * HID + b0 * HID);
        __syncthreads();

        float acc[4];
        {
            const float xv0 = x[((b0 + bb) * SEQT + t) * 3 + 0];
            const float xv1 = x[((b0 + bb) * SEQT + t) * 3 + 1];
            const float xv2 = x[((b0 + bb) * SEQT + t) * 3 + 2];
            #pragma unroll
            for (int u = 0; u < 4; ++u)
                acc[u] = bias1[u] + wx[u][0] * xv0 + wx[u][1] * xv1 + wx[u][2] * xv2;
        }

        #pragma unroll 4
        for (int k0 = 0; k0 < HID / 4; ++k0) {
            float4 hv = *(const float4*)&hs[bb][k0 * 4];
            #pragma unroll
            for (int u = 0; u < 4; ++u) {
                float4 wv = *(const float4*)&Whh0[grows[u] * HID + k0 * 4];
                acc[u] = fmaf(wv.x, hv.x, acc[u]);
                acc[u] = fmaf(wv.y, hv.y, acc[u]);
                acc[u] = fmaf(wv.z, hv.z, acc[u]);
                acc[u] = fmaf(wv.w, hv.w, acc[u]);
            }
        }

        *(float4*)&gbuf[bb][slot * 4] = make_float4(acc[0], acc[1], acc[2], acc[3]);
        __syncthreads();

        {
            float gi = gbuf[ub][uq];
            float gf = gbuf[ub][32 + uq];
            float gg = gbuf[ub][64 + uq];
            float go = gbuf[ub][96 + uq];
            float ii = sigm(gi), ff = sigm(gf), oo = sigm(go);
            float g2 = tanhf(gg);
            c1 = ff * c1 + ii * g2;
            float h = oo * tanhf(c1);
            h1ws[wsl * BATCH * HID + (b0 + ub) * HID + qabs] = h;
        }

        grid.sync();

        // ====================== Layer 2 ======================
        stage_h(hs, h1ws + wsl * BATCH * HID + b0 * HID);   // fresh h1_t
        __syncthreads();

        float acc2[4] = {bias2[0], bias2[1], bias2[2], bias2[3]};

        #pragma unroll 4
        for (int k0 = 0; k0 < HID / 4; ++k0) {
            float4 hv = *(const float4*)&hs[bb][k0 * 4];
            #pragma unroll
            for (int u = 0; u < 4; ++u) {
                float4 wv = *(const float4*)&Wih1[grows[u] * HID + k0 * 4];
                acc2[u] = fmaf(wv.x, hv.x, acc2[u]);
                acc2[u] = fmaf(wv.y, hv.y, acc2[u]);
                acc2[u] = fmaf(wv.z, hv.z, acc2[u]);
                acc2[u] = fmaf(wv.w, hv.w, acc2[u]);
            }
        }

        __syncthreads();   // done reading hs before restaging
        stage_h(hs, h2ws + rs * BATCH * HID + b0 * HID);    // h2_{t-1}
        __syncthreads();

        #pragma unroll 4
        for (int k0 = 0; k0 < HID / 4; ++k0) {
            float4 hv = *(const float4*)&hs[bb][k0 * 4];
            #pragma unroll
            for (int u = 0; u < 4; ++u) {
                float4 wv = *(const float4*)&Whh1[grows[u] * HID + k0 * 4];
                acc2[u] = fmaf(wv.x, hv.x, acc2[u]);
                acc2[u] = fmaf(wv.y, hv.y, acc2[u]);
                acc2[u] = fmaf(wv.z, hv.z, acc2[u]);
                acc2[u] = fmaf(wv.w, hv.w, acc2[u]);
            }
        }

        *(float4*)&gbuf[bb][slot * 4] = make_float4(acc2[0], acc2[1], acc2[2], acc2[3]);
        __syncthreads();

        {
            float gi = gbuf[ub][uq];
            float gf = gbuf[ub][32 + uq];
            float gg = gbuf[ub][64 + uq];
            float go = gbuf[ub][96 + uq];
            float ii = sigm(gi), ff = sigm(gf), oo = sigm(go);
            float g2 = tanhf(gg);
            c2 = ff * c2 + ii * g2;
            float h = oo * tanhf(c2);
            h2ws[wsl * BATCH * HID + (b0 + ub) * HID + qabs] = h;

            // FC: partial dot over this slice's 32 q, reduced across the 32-lane group
            float p0 = wfc0 * h;
            float p1 = wfc1 * h;
            float p2 = wfc2 * h;
            #pragma unroll
            for (int off = 16; off >= 1; off >>= 1) {
                p0 += __shfl_xor(p0, off);
                p1 += __shfl_xor(p1, off);
                p2 += __shfl_xor(p2, off);
            }
            if (uq == 0) {
                float* op = out + ((size_t)(b0 + ub) * SEQT + t) * 3;
                if (j == 0) {
                    atomicAdd(&op[0], p0 + bfc[0]);
                    atomicAdd(&op[1], p1 + bfc[1]);
                    atomicAdd(&op[2], p2 + bfc[2]);
                } else {
                    atomicAdd(&op[0], p0);
                    atomicAdd(&op[1], p1);
                    atomicAdd(&op[2], p2);
                }
            }
        }

        grid.sync();
    }
}

extern "C" void kernel_launch(void* const* d_in, const int* in_sizes, int n_in,
                              void* d_out, int out_size, void* d_ws, size_t ws_size,
                              hipStream_t stream)
{
    (void)in_sizes; (void)n_in; (void)ws_size;

    const float* x    = (const float*)d_in[0];
    const float* Wih0 = (const float*)d_in[1];
    const float* Whh0 = (const float*)d_in[2];
    const float* bih0 = (const float*)d_in[3];
    const float* bhh0 = (const float*)d_in[4];
    const float* Wih1 = (const float*)d_in[5];
    const float* Whh1 = (const float*)d_in[6];
    const float* bih1 = (const float*)d_in[7];
    const float* bhh1 = (const float*)d_in[8];
    const float* Wfc  = (const float*)d_in[9];
    const float* bfc  = (const float*)d_in[10];
    float* out = (float*)d_out;
    float* ws  = (float*)d_ws;

    // Zero output (atomics accumulate into it) and the h double-buffers.
    hipMemsetAsync(d_out, 0, (size_t)out_size * sizeof(float), stream);
    hipMemsetAsync(d_ws, 0, (size_t)4 * BATCH * HID * sizeof(float), stream);

    void* args[] = { (void*)&x, (void*)&Wih0, (void*)&Whh0, (void*)&bih0, (void*)&bhh0,
                     (void*)&Wih1, (void*)&Whh1, (void*)&bih1, (void*)&bhh1,
                     (void*)&Wfc, (void*)&bfc, (void*)&out, (void*)&ws };

    hipLaunchCooperativeKernel((const void*)lstm2_kernel, dim3(256), dim3(NTHR),
                               args, 0, stream);
}

// Round 3
// 11383.395 us; speedup vs baseline: 7.2713x; 7.2713x over previous
//
#include <hip/hip_runtime.h>
#include <stdint.h>

#define SEQT   512
#define HID    512
#define GRPS   8      // batch groups (32 batches each)
#define SLICES 32     // h-slices (16 h-indices x 4 gates = 64 gate rows each)
#define GB     32     // batches per group
#define NTHR   512

typedef __attribute__((ext_vector_type(8))) short bf16x8;
typedef __attribute__((ext_vector_type(4))) float f32x4;

// ---- d_ws layout (bytes) ----
// [0,12582912)        packed weights: 3 matrices x (hi 2MB + lo 2MB), A-frag order
// [12582912,14680064) h frag buffers: h1hi,h1lo,h2hi,h2lo each [2 par][8 grp][16384] bf16
// [14680064,+20480)   group barrier counters [8][640] u32
#define WMAT_ELEMS 1048576
#define WS_H_OFF   12582912
#define HBUF_ELEMS 16384
#define HARR_ELEMS 262144
#define WS_BAR_OFF 14680064
#define BAR_STRIDE 640
#define SMEM_BYTES 153600

__device__ __forceinline__ unsigned short f2bf(float x){
    unsigned int u = __float_as_uint(x);
    u = (u + 0x7fffu + ((u >> 16) & 1u)) >> 16;   // RNE
    return (unsigned short)u;
}
__device__ __forceinline__ float bf2f(unsigned short h){
    return __uint_as_float(((unsigned int)h) << 16);
}
__device__ __forceinline__ float sigm(float v){ return 1.0f / (1.0f + __expf(-v)); }
__device__ __forceinline__ float tanh_(float v){
    float e = __expf(2.0f * v);
    return (e - 1.0f) / (e + 1.0f);
}

// Pack W[2048][512] fp32 -> hi/lo bf16 in MFMA A-fragment order:
// element(jg, kt, lane, jj):  row = g*512 + j*16 + (lane&15), k = kt*32 + ((lane>>4)&3)*8 + jj
__global__ void prep_weights(const float* __restrict__ W0,
                             const float* __restrict__ W1,
                             const float* __restrict__ W2,
                             short* __restrict__ wp)
{
    const int mat = blockIdx.y;
    const float* src = (mat == 0) ? W0 : ((mat == 1) ? W1 : W2);
    short* dh = wp + (size_t)mat * (2 * WMAT_ELEMS);
    short* dl = dh + WMAT_ELEMS;
    const int jg = blockIdx.x;            // j*4 + g, 0..127
    const int j = jg >> 2, g = jg & 3;
    for (int rep = 0; rep < 2; ++rep){
        int task = rep * NTHR + (int)threadIdx.x;   // 0..1023 = (kt,lane)
        int kt = task >> 6, l = task & 63;
        int row = g * 512 + j * 16 + (l & 15);
        int k0  = kt * 32 + ((l >> 4) & 3) * 8;
        const float* s = src + (size_t)row * HID + k0;
        bf16x8 vh, vl;
        #pragma unroll
        for (int e = 0; e < 8; ++e){
            float v = s[e];
            unsigned short hb = f2bf(v);
            vh[e] = (short)hb;
            vl[e] = (short)f2bf(v - bf2f(hb));
        }
        size_t o = ((size_t)(jg * 16 + kt) * 64 + l) * 8;
        *(bf16x8*)(dh + o) = vh;
        *(bf16x8*)(dl + o) = vl;
    }
}

__global__ void __launch_bounds__(NTHR, 2)
lstm2_mfma(const float* __restrict__ x,
           const float* __restrict__ Wih0,
           const float* __restrict__ bih0, const float* __restrict__ bhh0,
           const float* __restrict__ bih1, const float* __restrict__ bhh1,
           const float* __restrict__ Wfc,  const float* __restrict__ bfc,
           float* __restrict__ out, char* __restrict__ ws)
{
    extern __shared__ char smem[];
    short* lh1h = (short*)smem;             // 16384 bf16 = 32KB (h1 hi, B-frag order)
    short* lh1l = lh1h + 16384;
    short* lh2h = lh1l + 16384;
    short* lh2l = lh2h + 16384;             // total 128KB
    float* g1   = (float*)(smem + 131072);  // [4 gate][2 n][16 q][16 b] = 8KB
    float* g2   = g1 + 2048;                // 8KB
    float* fcb  = g2 + 2048;                // [3][512] = 6KB

    const short* Wp  = (const short*)ws;
    const short* W0h = Wp;                      const short* W0l = Wp + WMAT_ELEMS;
    const short* W1h = Wp + 2 * WMAT_ELEMS;     const short* W1l = Wp + 3 * WMAT_ELEMS;
    const short* W2h = Wp + 4 * WMAT_ELEMS;     const short* W2l = Wp + 5 * WMAT_ELEMS;
    short* h1h_ws = (short*)(ws + WS_H_OFF);
    short* h1l_ws = h1h_ws + HARR_ELEMS;
    short* h2h_ws = h1h_ws + 2 * HARR_ELEMS;
    short* h2l_ws = h1h_ws + 3 * HARR_ELEMS;
    unsigned int* bar = (unsigned int*)(ws + WS_BAR_OFF);

    const int tid = threadIdx.x;
    const int wg  = blockIdx.x;
    const int grp = wg >> 5;          // 0..7   (wg&7 == j&7 -> weight slices co-locate per XCD)
    const int j   = wg & 31;          // h-slice 0..31

    // MFMA mapping: 8 waves = 4 gates x 2 k-halves
    const int wv = tid >> 6, lane = tid & 63;
    const int g  = wv >> 1, kh = wv & 1;
    const int ablk = (j * 4 + g) * 16;

    // pointwise mapping: 16 q x 32 b
    const int q  = tid >> 5, b = tid & 31;
    const int qg = j * 16 + q;
    const int nn = b >> 4, bl = b & 15;
    // B-frag element index of h(k=qg, col=b)
    const int eidx = (((qg >> 5) * 2 + nn) * 64 + ((qg >> 3) & 3) * 16 + bl) * 8 + (qg & 7);

    float bias1[4], bias2[4], wxr[4][3];
    #pragma unroll
    for (int gg = 0; gg < 4; ++gg){
        int row = gg * 512 + qg;
        bias1[gg] = bih0[row] + bhh0[row];
        bias2[gg] = bih1[row] + bhh1[row];
        wxr[gg][0] = Wih0[row * 3 + 0];
        wxr[gg][1] = Wih0[row * 3 + 1];
        wxr[gg][2] = Wih0[row * 3 + 2];
    }
    const float wf0 = Wfc[qg], wf1 = Wfc[512 + qg], wf2 = Wfc[1024 + qg];

    float c1 = 0.f, c2 = 0.f;

    // phase p: L1 computes t=p (p<512); L2 computes t=p-1 (p>=1). One barrier/phase.
    for (int p = 0; p <= SEQT; ++p){
        const int rs1 = (p + 1) & 1;   // slot of h1(p-1)
        const int rs2 = p & 1;         // slot of h2(p-2)

        // ---- stage h1(p-1), h2(p-2) frag buffers into LDS (linear 128KB copy) ----
        {
            const float4* s0 = (const float4*)(h1h_ws + (rs1 * GRPS + grp) * HBUF_ELEMS);
            const float4* s1 = (const float4*)(h1l_ws + (rs1 * GRPS + grp) * HBUF_ELEMS);
            const float4* s2 = (const float4*)(h2h_ws + (rs2 * GRPS + grp) * HBUF_ELEMS);
            const float4* s3 = (const float4*)(h2l_ws + (rs2 * GRPS + grp) * HBUF_ELEMS);
            float4* d0 = (float4*)lh1h; float4* d1 = (float4*)lh1l;
            float4* d2 = (float4*)lh2h; float4* d3 = (float4*)lh2l;
            #pragma unroll
            for (int r = 0; r < 4; ++r){
                int i4 = r * NTHR + tid;
                d0[i4] = s0[i4]; d1[i4] = s1[i4]; d2[i4] = s2[i4]; d3[i4] = s3[i4];
            }
        }
        __syncthreads();

        // ---- MFMA: gates1 = Whh0*h1 ; gates2 = Wih1*h1 + Whh1*h2 (bf16 3-mul split) ----
        f32x4 acc1[2] = {{0.f,0.f,0.f,0.f},{0.f,0.f,0.f,0.f}};
        f32x4 acc2[2] = {{0.f,0.f,0.f,0.f},{0.f,0.f,0.f,0.f}};
        #pragma unroll 2
        for (int ks = 0; ks < 8; ++ks){
            const int kt = kh * 8 + ks;
            const size_t ao = ((size_t)(ablk + kt) * 64 + lane) * 8;
            bf16x8 a0h = *(const bf16x8*)(W0h + ao);
            bf16x8 a0l = *(const bf16x8*)(W0l + ao);
            bf16x8 a1h = *(const bf16x8*)(W1h + ao);
            bf16x8 a1l = *(const bf16x8*)(W1l + ao);
            bf16x8 a2h = *(const bf16x8*)(W2h + ao);
            bf16x8 a2l = *(const bf16x8*)(W2l + ao);
            #pragma unroll
            for (int n = 0; n < 2; ++n){
                const int bo = ((kt * 2 + n) * 64 + lane) * 8;
                bf16x8 b1h = *(const bf16x8*)(lh1h + bo);
                bf16x8 b1l = *(const bf16x8*)(lh1l + bo);
                bf16x8 b2h = *(const bf16x8*)(lh2h + bo);
                bf16x8 b2l = *(const bf16x8*)(lh2l + bo);
                acc1[n] = __builtin_amdgcn_mfma_f32_16x16x32_bf16(a0h, b1h, acc1[n], 0, 0, 0);
                acc1[n] = __builtin_amdgcn_mfma_f32_16x16x32_bf16(a0h, b1l, acc1[n], 0, 0, 0);
                acc1[n] = __builtin_amdgcn_mfma_f32_16x16x32_bf16(a0l, b1h, acc1[n], 0, 0, 0);
                acc2[n] = __builtin_amdgcn_mfma_f32_16x16x32_bf16(a1h, b1h, acc2[n], 0, 0, 0);
                acc2[n] = __builtin_amdgcn_mfma_f32_16x16x32_bf16(a1h, b1l, acc2[n], 0, 0, 0);
                acc2[n] = __builtin_amdgcn_mfma_f32_16x16x32_bf16(a1l, b1h, acc2[n], 0, 0, 0);
                acc2[n] = __builtin_amdgcn_mfma_f32_16x16x32_bf16(a2h, b2h, acc2[n], 0, 0, 0);
                acc2[n] = __builtin_amdgcn_mfma_f32_16x16x32_bf16(a2h, b2l, acc2[n], 0, 0, 0);
                acc2[n] = __builtin_amdgcn_mfma_f32_16x16x32_bf16(a2l, b2h, acc2[n], 0, 0, 0);
            }
        }

        // ---- combine k-halves in LDS ----
        if (kh == 0){
            #pragma unroll
            for (int n = 0; n < 2; ++n)
                #pragma unroll
                for (int r = 0; r < 4; ++r){
                    int qrow = (lane >> 4) * 4 + r;
                    int idx = ((g * 2 + n) * 16 + qrow) * 16 + (lane & 15);
                    g1[idx] = acc1[n][r];
                    g2[idx] = acc2[n][r];
                }
        }
        __syncthreads();
        if (kh == 1){
            #pragma unroll
            for (int n = 0; n < 2; ++n)
                #pragma unroll
                for (int r = 0; r < 4; ++r){
                    int qrow = (lane >> 4) * 4 + r;
                    int idx = ((g * 2 + n) * 16 + qrow) * 16 + (lane & 15);
                    g1[idx] += acc1[n][r];
                    g2[idx] += acc2[n][r];
                }
        }
        __syncthreads();

        // ---- pointwise L1 (t = p) ----
        if (p < SEQT){
            float gt0 = bias1[0] + g1[((0 * 2 + nn) * 16 + q) * 16 + bl];
            float gt1 = bias1[1] + g1[((1 * 2 + nn) * 16 + q) * 16 + bl];
            float gt2 = bias1[2] + g1[((2 * 2 + nn) * 16 + q) * 16 + bl];
            float gt3 = bias1[3] + g1[((3 * 2 + nn) * 16 + q) * 16 + bl];
            const float* xp = x + ((size_t)(grp * GB + b) * SEQT + p) * 3;
            float x0 = xp[0], x1 = xp[1], x2 = xp[2];
            gt0 += wxr[0][0] * x0 + wxr[0][1] * x1 + wxr[0][2] * x2;
            gt1 += wxr[1][0] * x0 + wxr[1][1] * x1 + wxr[1][2] * x2;
            gt2 += wxr[2][0] * x0 + wxr[2][1] * x1 + wxr[2][2] * x2;
            gt3 += wxr[3][0] * x0 + wxr[3][1] * x1 + wxr[3][2] * x2;
            float ii = sigm(gt0), ff = sigm(gt1), gv = tanh_(gt2), oo = sigm(gt3);
            c1 = ff * c1 + ii * gv;
            float h = oo * tanh_(c1);
            unsigned short hb = f2bf(h);
            unsigned short lb = f2bf(h - bf2f(hb));
            int base = ((p & 1) * GRPS + grp) * HBUF_ELEMS;
            h1h_ws[base + eidx] = (short)hb;
            h1l_ws[base + eidx] = (short)lb;
        }

        // ---- pointwise L2 (t = p-1) + FC partials ----
        if (p >= 1){
            float gt0 = bias2[0] + g2[((0 * 2 + nn) * 16 + q) * 16 + bl];
            float gt1 = bias2[1] + g2[((1 * 2 + nn) * 16 + q) * 16 + bl];
            float gt2 = bias2[2] + g2[((2 * 2 + nn) * 16 + q) * 16 + bl];
            float gt3 = bias2[3] + g2[((3 * 2 + nn) * 16 + q) * 16 + bl];
            float ii = sigm(gt0), ff = sigm(gt1), gv = tanh_(gt2), oo = sigm(gt3);
            c2 = ff * c2 + ii * gv;
            float h = oo * tanh_(c2);
            unsigned short hb = f2bf(h);
            unsigned short lb = f2bf(h - bf2f(hb));
            int base = (((p - 1) & 1) * GRPS + grp) * HBUF_ELEMS;
            h2h_ws[base + eidx] = (short)hb;
            h2l_ws[base + eidx] = (short)lb;
            fcb[0 * 512 + tid] = wf0 * h;
            fcb[1 * 512 + tid] = wf1 * h;
            fcb[2 * 512 + tid] = wf2 * h;
        }
        __syncthreads();
        if (p >= 1 && tid < 96){
            int d = tid >> 5, bb = tid & 31;
            float s = 0.f;
            #pragma unroll
            for (int qq = 0; qq < 16; ++qq) s += fcb[d * 512 + qq * 32 + bb];
            if (j == 0) s += bfc[d];
            atomicAdd(out + ((size_t)(grp * GB + bb) * SEQT + (p - 1)) * 3 + d, s);
        }

        // ---- group barrier (32 WGs of this batch group) ----
        if (tid == 0){
            unsigned int* c = bar + grp * BAR_STRIDE + p;
            __hip_atomic_fetch_add(c, 1u, __ATOMIC_RELEASE, __HIP_MEMORY_SCOPE_AGENT);
            while (__hip_atomic_load(c, __ATOMIC_RELAXED, __HIP_MEMORY_SCOPE_AGENT) < (unsigned)SLICES) {}
            __builtin_amdgcn_fence(__ATOMIC_ACQUIRE, "agent");
        }
        __syncthreads();
    }
}

extern "C" void kernel_launch(void* const* d_in, const int* in_sizes, int n_in,
                              void* d_out, int out_size, void* d_ws, size_t ws_size,
                              hipStream_t stream)
{
    (void)in_sizes; (void)n_in; (void)ws_size;

    const float* x    = (const float*)d_in[0];
    const float* Wih0 = (const float*)d_in[1];
    const float* Whh0 = (const float*)d_in[2];
    const float* bih0 = (const float*)d_in[3];
    const float* bhh0 = (const float*)d_in[4];
    const float* Wih1 = (const float*)d_in[5];
    const float* Whh1 = (const float*)d_in[6];
    const float* bih1 = (const float*)d_in[7];
    const float* bhh1 = (const float*)d_in[8];
    const float* Wfc  = (const float*)d_in[9];
    const float* bfc  = (const float*)d_in[10];
    float* out = (float*)d_out;
    char*  ws  = (char*)d_ws;

    // zero h exchange buffers, barrier counters, and the atomically-accumulated output
    hipMemsetAsync(ws + WS_H_OFF, 0, 4 * HARR_ELEMS * sizeof(short), stream);
    hipMemsetAsync(ws + WS_BAR_OFF, 0, GRPS * BAR_STRIDE * sizeof(unsigned int), stream);
    hipMemsetAsync(d_out, 0, (size_t)out_size * sizeof(float), stream);

    // pack weights into MFMA fragment order (d_ws is re-poisoned before every launch)
    prep_weights<<<dim3(128, 3), NTHR, 0, stream>>>(Whh0, Wih1, Whh1, (short*)ws);

    hipFuncSetAttribute((const void*)lstm2_mfma,
                        hipFuncAttributeMaxDynamicSharedMemorySize, SMEM_BYTES);

    void* args[] = { (void*)&x, (void*)&Wih0, (void*)&bih0, (void*)&bhh0,
                     (void*)&bih1, (void*)&bhh1, (void*)&Wfc, (void*)&bfc,
                     (void*)&out, (void*)&ws };
    hipLaunchCooperativeKernel((const void*)lstm2_mfma, dim3(GRPS * SLICES), dim3(NTHR),
                               args, SMEM_BYTES, stream);
}